// Round 10
// baseline (61.485 us; speedup 1.0000x reference)
//
#include <hip/hip_runtime.h>
#include <stdint.h>

// ---------------------------------------------------------------------------
// AdditiveAttention (Bahdanau) + gumbel-softmax(tau=0.01), channel 0.
//
// R10 = MEASUREMENT ROUND. proj_kernel and attn_kernel are byte-identical
// to R9 (passing, 46.7us total). A third SHADOW kernel (attn_loop_probe)
// replicates ONLY the staging + inner h4 loop and stores raw accumulators
// to an unused d_ws region (keeps it live, doesn't touch d_out).
//   S_loop = dur_R10 - 46.7us   (kernels serialize on stream)
// Pre-committed: S>=30us -> loop structurally pinned, restructure layout;
// S<=16us -> loop fine, attack epilogue/proj next.
// ---------------------------------------------------------------------------

#define BB 4
#define LLEN 512
#define DD 256
#define HH 128

#define TWO_LOG2E 2.8853900817779268f   // 2*log2(e)
#define LOG2E_100 144.26950408889634f   // 100*log2(e)

__device__ __forceinline__ uint32_t rotl32(uint32_t v, int r) {
  return (v << r) | (v >> (32 - r));
}

// Threefry-2x32, key = (0, 42)
__device__ __forceinline__ void tf2x32(uint32_t x0, uint32_t x1,
                                       uint32_t& o0, uint32_t& o1) {
  const uint32_t k0 = 0u;
  const uint32_t k1 = 42u;
  const uint32_t k2 = 0x1BD11BDAu ^ k0 ^ k1;

  x0 += k0; x1 += k1;
#define TFR(r) { x0 += x1; x1 = rotl32(x1, (r)); x1 ^= x0; }
  TFR(13) TFR(15) TFR(26) TFR(6)
  x0 += k1; x1 += k2 + 1u;
  TFR(17) TFR(29) TFR(16) TFR(24)
  x0 += k2; x1 += k0 + 2u;
  TFR(13) TFR(15) TFR(26) TFR(6)
  x0 += k0; x1 += k1 + 3u;
  TFR(17) TFR(29) TFR(16) TFR(24)
  x0 += k1; x1 += k2 + 4u;
  TFR(13) TFR(15) TFR(26) TFR(6)
  x0 += k2; x1 += k0 + 5u;
#undef TFR
  o0 = x0; o1 = x1;
}

// u in (0,1) from jax partitionable random_bits (counter (0,flat), o0^o1)
__device__ __forceinline__ float jax_u01(uint32_t flat) {
  uint32_t o0, o1;
  tf2x32(0u, flat, o0, o1);
  const uint32_t bits = o0 ^ o1;
  const float f = __uint_as_float((bits >> 9) | 0x3F800000u) - 1.0f;
  return fmaxf(f, 1.17549435e-38f);
}

// ---------------------------------------------------------------------------
// Kernel A: projections -> EQ = exp2(c * q.Wq^T), EK = exp2(c * k.Wk^T).
// (identical to R9)
// ---------------------------------------------------------------------------
__global__ __launch_bounds__(128) void proj_kernel(
    const float* __restrict__ queries, const float* __restrict__ keys,
    const float* __restrict__ Wq, const float* __restrict__ Wk,
    float* __restrict__ EQ, float* __restrict__ EK) {
  const int blk = blockIdx.x;
  const bool isK = blk >= 512;
  const int rb = (isK ? blk - 512 : blk) * 4;   // rows rb..rb+3 (of 2048)
  const float* __restrict__ in = isK ? keys : queries;
  const float* __restrict__ W  = isK ? Wk : Wq;
  float* __restrict__ outp     = isK ? EK : EQ;

  __shared__ float rows[4][DD];
  const float4* in4 = reinterpret_cast<const float4*>(in + (size_t)rb * DD);
  float4* rows4 = reinterpret_cast<float4*>(&rows[0][0]);
  #pragma unroll
  for (int t = threadIdx.x; t < 4 * DD / 4; t += 128) rows4[t] = in4[t];
  __syncthreads();

  const int h = threadIdx.x;
  const float4* W4 = reinterpret_cast<const float4*>(W + (size_t)h * DD);
  float a0 = 0.f, a1 = 0.f, a2 = 0.f, a3 = 0.f;
  #pragma unroll 8
  for (int d4 = 0; d4 < DD / 4; ++d4) {
    const float4 w = W4[d4];
    const int d = d4 * 4;
    a0 = fmaf(w.x, rows[0][d], fmaf(w.y, rows[0][d+1], fmaf(w.z, rows[0][d+2], fmaf(w.w, rows[0][d+3], a0))));
    a1 = fmaf(w.x, rows[1][d], fmaf(w.y, rows[1][d+1], fmaf(w.z, rows[1][d+2], fmaf(w.w, rows[1][d+3], a1))));
    a2 = fmaf(w.x, rows[2][d], fmaf(w.y, rows[2][d+1], fmaf(w.z, rows[2][d+2], fmaf(w.w, rows[2][d+3], a2))));
    a3 = fmaf(w.x, rows[3][d], fmaf(w.y, rows[3][d+1], fmaf(w.z, rows[3][d+2], fmaf(w.w, rows[3][d+3], a3))));
  }
  float* orow = outp + (size_t)rb * HH + h;
  orow[0 * HH] = __builtin_amdgcn_exp2f(a0 * TWO_LOG2E);
  orow[1 * HH] = __builtin_amdgcn_exp2f(a1 * TWO_LOG2E);
  orow[2 * HH] = __builtin_amdgcn_exp2f(a2 * TWO_LOG2E);
  orow[3 * HH] = __builtin_amdgcn_exp2f(a3 * TWO_LOG2E);
}

// ---------------------------------------------------------------------------
// Shared-rcp 4-group site macro (identical to R9)
// ---------------------------------------------------------------------------
#define GRP(accv, qv, kv, wd) {                                       \
    float4 A_;                                                        \
    A_.x = fmaf((qv).x, (kv).x, 1.0f);                                \
    A_.y = fmaf((qv).y, (kv).y, 1.0f);                                \
    A_.z = fmaf((qv).z, (kv).z, 1.0f);                                \
    A_.w = fmaf((qv).w, (kv).w, 1.0f);                                \
    const float p01_ = A_.x * A_.y;                                   \
    const float p23_ = A_.z * A_.w;                                   \
    const float n01_ = fmaf((wd).x, A_.y, (wd).y * A_.x);             \
    const float n23_ = fmaf((wd).z, A_.w, (wd).w * A_.z);             \
    const float num_ = fmaf(n01_, p23_, n23_ * p01_);                 \
    const float rc_  = __builtin_amdgcn_rcpf(p01_ * p23_);            \
    (accv) = fmaf(num_, rc_, (accv)); }

// ---------------------------------------------------------------------------
// Kernel B: 16i x 64j tile (grid 32x8x4), 256 threads, 4 outputs/thread.
// (identical to R9)
// ---------------------------------------------------------------------------
__global__ __launch_bounds__(256) void attn_kernel(
    const float* __restrict__ EQ, const float* __restrict__ EK,
    const int* __restrict__ mask, const float* __restrict__ Wv,
    float* __restrict__ out) {
  __shared__ float4 QL[16][33];
  __shared__ float4 KL[64][33];
  __shared__ float4 wdL[32];

  const int bi = blockIdx.x, bj = blockIdx.y, b = blockIdx.z;
  const int i0 = bi * 16, j0 = bj * 64;

  const float4* Q4 = reinterpret_cast<const float4*>(EQ) + ((size_t)b * LLEN + i0) * (HH / 4);
  const float4* K4 = reinterpret_cast<const float4*>(EK) + ((size_t)b * LLEN + j0) * (HH / 4);
  for (int t = threadIdx.x; t < 512 + 2048; t += 256) {
    if (t < 512) {
      QL[t >> 5][t & 31] = Q4[t];
    } else {
      const int u = t - 512;
      KL[u >> 5][u & 31] = K4[u];
    }
  }
  if (threadIdx.x < 32) {
    const float4 w0 = reinterpret_cast<const float4*>(Wv)[threadIdx.x];
    const float4 w1 = reinterpret_cast<const float4*>(Wv)[32 + threadIdx.x];
    float4 wd; wd.x = w0.x - w1.x; wd.y = w0.y - w1.y;
    wd.z = w0.z - w1.z; wd.w = w0.w - w1.w;
    wdL[threadIdx.x] = wd;
  }
  __syncthreads();

  const int jj = threadIdx.x & 31;
  const int ib = threadIdx.x >> 5;

  const uint32_t row0 = (uint32_t)b * LLEN + i0 + ib;
  const uint32_t col0 = j0 + jj;
  const uint32_t idx00 = row0 * LLEN + col0;
  const uint32_t idx01 = idx00 + 32u;
  const uint32_t idx10 = idx00 + 8u * LLEN;
  const uint32_t idx11 = idx10 + 32u;
  const int m00 = mask[idx00], m01 = mask[idx01];
  const int m10 = mask[idx10], m11 = mask[idx11];

  float Swd = 0.f;
  #pragma unroll
  for (int t = 0; t < 32; ++t) {
    const float4 wd = wdL[t];
    Swd += (wd.x + wd.y) + (wd.z + wd.w);
  }

  float acc00 = 0.f, acc01 = 0.f, acc10 = 0.f, acc11 = 0.f;

  #pragma unroll 4
  for (int h4 = 0; h4 < HH / 4; ++h4) {
    const float4 kv0 = KL[jj][h4];
    const float4 kv1 = KL[jj + 32][h4];
    const float4 qv0 = QL[ib][h4];
    const float4 qv1 = QL[ib + 8][h4];
    const float4 wd  = wdL[h4];
    GRP(acc00, qv0, kv0, wd)
    GRP(acc01, qv0, kv1, wd)
    GRP(acc10, qv1, kv0, wd)
    GRP(acc11, qv1, kv1, wd)
  }

  #define EPI(accv, mreg, idx) {                                        \
      float o_ = 1.0f;                                                  \
      if ((mreg) >= 2) {                                                \
        const float d_  = fmaf(-2.0f, (accv), Swd);                     \
        const float l0_ = __log2f(jax_u01((idx) * 2u));                 \
        const float l1_ = __log2f(jax_u01((idx) * 2u + 1u));            \
        const float rl_ = l1_ * __builtin_amdgcn_rcpf(l0_);             \
        const float dl_ = __log2f(rl_);                                 \
        const float t_  = fmaf(d_, LOG2E_100, 100.0f * dl_);            \
        o_ = __builtin_amdgcn_rcpf(1.0f + __builtin_amdgcn_exp2f(-t_)); \
      }                                                                 \
      out[idx] = o_; }

  EPI(acc00, m00, idx00)
  EPI(acc01, m01, idx01)
  EPI(acc10, m10, idx10)
  EPI(acc11, m11, idx11)
  #undef EPI
}

// ---------------------------------------------------------------------------
// SHADOW PROBE: staging + inner loop ONLY. Stores raw acc to d_ws region.
// S_loop = dur_R10 - dur_R9. Runs LAST (no cache warming for attn_kernel).
// ---------------------------------------------------------------------------
__global__ __launch_bounds__(256) void attn_loop_probe(
    const float* __restrict__ EQ, const float* __restrict__ EK,
    const float* __restrict__ Wv, float* __restrict__ pout) {
  __shared__ float4 QL[16][33];
  __shared__ float4 KL[64][33];
  __shared__ float4 wdL[32];

  const int bi = blockIdx.x, bj = blockIdx.y, b = blockIdx.z;
  const int i0 = bi * 16, j0 = bj * 64;

  const float4* Q4 = reinterpret_cast<const float4*>(EQ) + ((size_t)b * LLEN + i0) * (HH / 4);
  const float4* K4 = reinterpret_cast<const float4*>(EK) + ((size_t)b * LLEN + j0) * (HH / 4);
  for (int t = threadIdx.x; t < 512 + 2048; t += 256) {
    if (t < 512) {
      QL[t >> 5][t & 31] = Q4[t];
    } else {
      const int u = t - 512;
      KL[u >> 5][u & 31] = K4[u];
    }
  }
  if (threadIdx.x < 32) {
    const float4 w0 = reinterpret_cast<const float4*>(Wv)[threadIdx.x];
    const float4 w1 = reinterpret_cast<const float4*>(Wv)[32 + threadIdx.x];
    float4 wd; wd.x = w0.x - w1.x; wd.y = w0.y - w1.y;
    wd.z = w0.z - w1.z; wd.w = w0.w - w1.w;
    wdL[threadIdx.x] = wd;
  }
  __syncthreads();

  const int jj = threadIdx.x & 31;
  const int ib = threadIdx.x >> 5;

  float acc00 = 0.f, acc01 = 0.f, acc10 = 0.f, acc11 = 0.f;

  #pragma unroll 4
  for (int h4 = 0; h4 < HH / 4; ++h4) {
    const float4 kv0 = KL[jj][h4];
    const float4 kv1 = KL[jj + 32][h4];
    const float4 qv0 = QL[ib][h4];
    const float4 qv1 = QL[ib + 8][h4];
    const float4 wd  = wdL[h4];
    GRP(acc00, qv0, kv0, wd)
    GRP(acc01, qv0, kv1, wd)
    GRP(acc10, qv1, kv0, wd)
    GRP(acc11, qv1, kv1, wd)
  }

  // coalesced store of raw accs keeps everything live
  const uint32_t tg = (((uint32_t)blockIdx.z * gridDim.y + blockIdx.y) * gridDim.x
                       + blockIdx.x) * 256u + threadIdx.x;
  float4 v; v.x = acc00; v.y = acc01; v.z = acc10; v.w = acc11;
  reinterpret_cast<float4*>(pout)[tg] = v;
}

extern "C" void kernel_launch(void* const* d_in, const int* in_sizes, int n_in,
                              void* d_out, int out_size, void* d_ws, size_t ws_size,
                              hipStream_t stream) {
  const float* queries = (const float*)d_in[0];
  const float* keys    = (const float*)d_in[1];
  const int*   mask    = (const int*)d_in[2];
  const float* Wq      = (const float*)d_in[3];
  const float* Wk      = (const float*)d_in[4];
  const float* Wv      = (const float*)d_in[5];
  float* out = (float*)d_out;

  float* EQ = (float*)d_ws;                 // [2048][128]
  float* EK = EQ + (size_t)BB * LLEN * HH;  // [2048][128]
  float* probe = EK + (size_t)BB * LLEN * HH;  // 4 MB probe region

  proj_kernel<<<dim3(1024), dim3(128), 0, stream>>>(
      queries, keys, Wq, Wk, EQ, EK);
  attn_kernel<<<dim3(LLEN / 16, LLEN / 64, BB), dim3(256), 0, stream>>>(
      EQ, EK, mask, Wv, out);
  attn_loop_probe<<<dim3(LLEN / 16, LLEN / 64, BB), dim3(256), 0, stream>>>(
      EQ, EK, Wv, probe);
}

// Round 11
// 49.137 us; speedup vs baseline: 1.2513x; 1.2513x over previous
//
#include <hip/hip_runtime.h>
#include <stdint.h>

// ---------------------------------------------------------------------------
// AdditiveAttention (Bahdanau) + gumbel-softmax(tau=0.01), channel 0.
//
// R11 = SPLIT round (probe + fix in one). R10 measured loop+staging = 14.8us
// => epilogue+mask+stores ~25us, 10x my op model. Two hypotheses:
//  (a) epilogue interferes with loop codegen (pressure/exec-mask regions)
//  (b) threefry+logs intrinsically expensive
// Split distinguishes them AND is the fix for (a):
//   attn_loop: staging + h4 loop only (== measured 14us probe), stores
//              d = Swd - 2*acc per output to d_ws.
//   attn_epi:  branchless, LDS-free, low-VGPR kernel: reads d + mask,
//              8 independent threefry chains, writes out.
// Pre-committed: total<=31us -> (a) confirmed; total>=42us -> (b).
// ---------------------------------------------------------------------------

#define BB 4
#define LLEN 512
#define DD 256
#define HH 128

#define TWO_LOG2E 2.8853900817779268f   // 2*log2(e)
#define LOG2E_100 144.26950408889634f   // 100*log2(e)

__device__ __forceinline__ uint32_t rotl32(uint32_t v, int r) {
  return (v << r) | (v >> (32 - r));
}

// Threefry-2x32, key = (0, 42)
__device__ __forceinline__ void tf2x32(uint32_t x0, uint32_t x1,
                                       uint32_t& o0, uint32_t& o1) {
  const uint32_t k0 = 0u;
  const uint32_t k1 = 42u;
  const uint32_t k2 = 0x1BD11BDAu ^ k0 ^ k1;

  x0 += k0; x1 += k1;
#define TFR(r) { x0 += x1; x1 = rotl32(x1, (r)); x1 ^= x0; }
  TFR(13) TFR(15) TFR(26) TFR(6)
  x0 += k1; x1 += k2 + 1u;
  TFR(17) TFR(29) TFR(16) TFR(24)
  x0 += k2; x1 += k0 + 2u;
  TFR(13) TFR(15) TFR(26) TFR(6)
  x0 += k0; x1 += k1 + 3u;
  TFR(17) TFR(29) TFR(16) TFR(24)
  x0 += k1; x1 += k2 + 4u;
  TFR(13) TFR(15) TFR(26) TFR(6)
  x0 += k2; x1 += k0 + 5u;
#undef TFR
  o0 = x0; o1 = x1;
}

// u in (0,1) from jax partitionable random_bits (counter (0,flat), o0^o1)
__device__ __forceinline__ float jax_u01(uint32_t flat) {
  uint32_t o0, o1;
  tf2x32(0u, flat, o0, o1);
  const uint32_t bits = o0 ^ o1;
  const float f = __uint_as_float((bits >> 9) | 0x3F800000u) - 1.0f;
  return fmaxf(f, 1.17549435e-38f);
}

// ---------------------------------------------------------------------------
// Kernel A: projections -> EQ = exp2(c * q.Wq^T), EK = exp2(c * k.Wk^T).
// (identical to R9)
// ---------------------------------------------------------------------------
__global__ __launch_bounds__(128) void proj_kernel(
    const float* __restrict__ queries, const float* __restrict__ keys,
    const float* __restrict__ Wq, const float* __restrict__ Wk,
    float* __restrict__ EQ, float* __restrict__ EK) {
  const int blk = blockIdx.x;
  const bool isK = blk >= 512;
  const int rb = (isK ? blk - 512 : blk) * 4;
  const float* __restrict__ in = isK ? keys : queries;
  const float* __restrict__ W  = isK ? Wk : Wq;
  float* __restrict__ outp     = isK ? EK : EQ;

  __shared__ float rows[4][DD];
  const float4* in4 = reinterpret_cast<const float4*>(in + (size_t)rb * DD);
  float4* rows4 = reinterpret_cast<float4*>(&rows[0][0]);
  #pragma unroll
  for (int t = threadIdx.x; t < 4 * DD / 4; t += 128) rows4[t] = in4[t];
  __syncthreads();

  const int h = threadIdx.x;
  const float4* W4 = reinterpret_cast<const float4*>(W + (size_t)h * DD);
  float a0 = 0.f, a1 = 0.f, a2 = 0.f, a3 = 0.f;
  #pragma unroll 8
  for (int d4 = 0; d4 < DD / 4; ++d4) {
    const float4 w = W4[d4];
    const int d = d4 * 4;
    a0 = fmaf(w.x, rows[0][d], fmaf(w.y, rows[0][d+1], fmaf(w.z, rows[0][d+2], fmaf(w.w, rows[0][d+3], a0))));
    a1 = fmaf(w.x, rows[1][d], fmaf(w.y, rows[1][d+1], fmaf(w.z, rows[1][d+2], fmaf(w.w, rows[1][d+3], a1))));
    a2 = fmaf(w.x, rows[2][d], fmaf(w.y, rows[2][d+1], fmaf(w.z, rows[2][d+2], fmaf(w.w, rows[2][d+3], a2))));
    a3 = fmaf(w.x, rows[3][d], fmaf(w.y, rows[3][d+1], fmaf(w.z, rows[3][d+2], fmaf(w.w, rows[3][d+3], a3))));
  }
  float* orow = outp + (size_t)rb * HH + h;
  orow[0 * HH] = __builtin_amdgcn_exp2f(a0 * TWO_LOG2E);
  orow[1 * HH] = __builtin_amdgcn_exp2f(a1 * TWO_LOG2E);
  orow[2 * HH] = __builtin_amdgcn_exp2f(a2 * TWO_LOG2E);
  orow[3 * HH] = __builtin_amdgcn_exp2f(a3 * TWO_LOG2E);
}

// ---------------------------------------------------------------------------
// Shared-rcp 4-group site macro (identical to R9)
// ---------------------------------------------------------------------------
#define GRP(accv, qv, kv, wd) {                                       \
    float4 A_;                                                        \
    A_.x = fmaf((qv).x, (kv).x, 1.0f);                                \
    A_.y = fmaf((qv).y, (kv).y, 1.0f);                                \
    A_.z = fmaf((qv).z, (kv).z, 1.0f);                                \
    A_.w = fmaf((qv).w, (kv).w, 1.0f);                                \
    const float p01_ = A_.x * A_.y;                                   \
    const float p23_ = A_.z * A_.w;                                   \
    const float n01_ = fmaf((wd).x, A_.y, (wd).y * A_.x);             \
    const float n23_ = fmaf((wd).z, A_.w, (wd).w * A_.z);             \
    const float num_ = fmaf(n01_, p23_, n23_ * p01_);                 \
    const float rc_  = __builtin_amdgcn_rcpf(p01_ * p23_);            \
    (accv) = fmaf(num_, rc_, (accv)); }

// ---------------------------------------------------------------------------
// Kernel B1: staging + h4 loop ONLY (== R10 probe). Stores d = Swd - 2*acc.
// ---------------------------------------------------------------------------
__global__ __launch_bounds__(256) void attn_loop(
    const float* __restrict__ EQ, const float* __restrict__ EK,
    const float* __restrict__ Wv, float* __restrict__ dbuf) {
  __shared__ float4 QL[16][33];
  __shared__ float4 KL[64][33];
  __shared__ float4 wdL[32];

  const int bi = blockIdx.x, bj = blockIdx.y, b = blockIdx.z;
  const int i0 = bi * 16, j0 = bj * 64;

  const float4* Q4 = reinterpret_cast<const float4*>(EQ) + ((size_t)b * LLEN + i0) * (HH / 4);
  const float4* K4 = reinterpret_cast<const float4*>(EK) + ((size_t)b * LLEN + j0) * (HH / 4);
  for (int t = threadIdx.x; t < 512 + 2048; t += 256) {
    if (t < 512) {
      QL[t >> 5][t & 31] = Q4[t];
    } else {
      const int u = t - 512;
      KL[u >> 5][u & 31] = K4[u];
    }
  }
  if (threadIdx.x < 32) {
    const float4 w0 = reinterpret_cast<const float4*>(Wv)[threadIdx.x];
    const float4 w1 = reinterpret_cast<const float4*>(Wv)[32 + threadIdx.x];
    float4 wd; wd.x = w0.x - w1.x; wd.y = w0.y - w1.y;
    wd.z = w0.z - w1.z; wd.w = w0.w - w1.w;
    wdL[threadIdx.x] = wd;
  }
  __syncthreads();

  const int jj = threadIdx.x & 31;
  const int ib = threadIdx.x >> 5;

  float Swd = 0.f;
  #pragma unroll
  for (int t = 0; t < 32; ++t) {
    const float4 wd = wdL[t];
    Swd += (wd.x + wd.y) + (wd.z + wd.w);
  }

  float acc00 = 0.f, acc01 = 0.f, acc10 = 0.f, acc11 = 0.f;

  #pragma unroll 4
  for (int h4 = 0; h4 < HH / 4; ++h4) {
    const float4 kv0 = KL[jj][h4];
    const float4 kv1 = KL[jj + 32][h4];
    const float4 qv0 = QL[ib][h4];
    const float4 qv1 = QL[ib + 8][h4];
    const float4 wd  = wdL[h4];
    GRP(acc00, qv0, kv0, wd)
    GRP(acc01, qv0, kv1, wd)
    GRP(acc10, qv1, kv0, wd)
    GRP(acc11, qv1, kv1, wd)
  }

  const uint32_t tg = (((uint32_t)blockIdx.z * gridDim.y + blockIdx.y) * gridDim.x
                       + blockIdx.x) * 256u + threadIdx.x;
  float4 v;
  v.x = fmaf(-2.0f, acc00, Swd);
  v.y = fmaf(-2.0f, acc01, Swd);
  v.z = fmaf(-2.0f, acc10, Swd);
  v.w = fmaf(-2.0f, acc11, Swd);
  reinterpret_cast<float4*>(dbuf)[tg] = v;
}

// ---------------------------------------------------------------------------
// Kernel B2: epilogue. Branchless, LDS-free, low-VGPR: reads d + mask,
// 8 independent threefry chains per thread, writes out.
// Same grid/thread->output mapping as attn_loop.
// ---------------------------------------------------------------------------
__global__ __launch_bounds__(256) void attn_epi(
    const float* __restrict__ dbuf, const int* __restrict__ mask,
    float* __restrict__ out) {
  const int bi = blockIdx.x, bj = blockIdx.y, b = blockIdx.z;
  const int i0 = bi * 16, j0 = bj * 64;
  const int jj = threadIdx.x & 31;
  const int ib = threadIdx.x >> 5;

  const uint32_t tg = (((uint32_t)blockIdx.z * gridDim.y + blockIdx.y) * gridDim.x
                       + blockIdx.x) * 256u + threadIdx.x;
  const float4 d4 = reinterpret_cast<const float4*>(dbuf)[tg];

  const uint32_t row0 = (uint32_t)b * LLEN + i0 + ib;
  const uint32_t col0 = j0 + jj;
  const uint32_t idx00 = row0 * LLEN + col0;
  const uint32_t idx01 = idx00 + 32u;
  const uint32_t idx10 = idx00 + 8u * LLEN;
  const uint32_t idx11 = idx10 + 32u;

  const int m00 = mask[idx00], m01 = mask[idx01];
  const int m10 = mask[idx10], m11 = mask[idx11];

  // branchless epilogue: always compute, select on mask
  #define EPI(dv, mreg, idx) {                                          \
      const float l0_ = __log2f(jax_u01((idx) * 2u));                   \
      const float l1_ = __log2f(jax_u01((idx) * 2u + 1u));              \
      const float rl_ = l1_ * __builtin_amdgcn_rcpf(l0_);               \
      const float dl_ = __log2f(rl_);                                   \
      const float t_  = fmaf((dv), LOG2E_100, 100.0f * dl_);            \
      const float oc_ = __builtin_amdgcn_rcpf(1.0f + __builtin_amdgcn_exp2f(-t_)); \
      out[idx] = ((mreg) >= 2) ? oc_ : 1.0f; }

  EPI(d4.x, m00, idx00)
  EPI(d4.y, m01, idx01)
  EPI(d4.z, m10, idx10)
  EPI(d4.w, m11, idx11)
  #undef EPI
}

extern "C" void kernel_launch(void* const* d_in, const int* in_sizes, int n_in,
                              void* d_out, int out_size, void* d_ws, size_t ws_size,
                              hipStream_t stream) {
  const float* queries = (const float*)d_in[0];
  const float* keys    = (const float*)d_in[1];
  const int*   mask    = (const int*)d_in[2];
  const float* Wq      = (const float*)d_in[3];
  const float* Wk      = (const float*)d_in[4];
  const float* Wv      = (const float*)d_in[5];
  float* out = (float*)d_out;

  float* EQ   = (float*)d_ws;                  // [2048][128] 1 MB
  float* EK   = EQ + (size_t)BB * LLEN * HH;   // [2048][128] 1 MB
  float* dbuf = EK + (size_t)BB * LLEN * HH;   // 4 MB (per-output d values)

  proj_kernel<<<dim3(1024), dim3(128), 0, stream>>>(
      queries, keys, Wq, Wk, EQ, EK);
  attn_loop<<<dim3(LLEN / 16, LLEN / 64, BB), dim3(256), 0, stream>>>(
      EQ, EK, Wv, dbuf);
  attn_epi<<<dim3(LLEN / 16, LLEN / 64, BB), dim3(256), 0, stream>>>(
      dbuf, mask, out);
}

// Round 12
// 47.218 us; speedup vs baseline: 1.3022x; 1.0406x over previous
//
#include <hip/hip_runtime.h>
#include <stdint.h>

// ---------------------------------------------------------------------------
// AdditiveAttention (Bahdanau) + gumbel-softmax(tau=0.01), channel 0.
//
// out[b,i,j] = (mask==1) ? 1.0 : sigmoid((d + g0 - g1)*100),
//   d = sum_h tanh(q+k)*(w0-w1);  g bit-exact jax threefry (verified R3-R11).
//
// R12 model (fits R3-R11): per-CU cost = max(VALU-issue, trans@16cy/wave-op,
// LDS-b128@12cy shared per CU, HBM). Loop was LDS-bound (14.8us), epi is
// ~25us of threefry over ALL sites (masks mixed within waves -> no skip).
//  - loop: 32i x 64j tile, 8 out/thread -> 7 LDS reads / 8 site-groups
//    (was 5/4): LDS floor 12.8 -> 9.0us.
//  - wave-local compaction (ballot+popcount rank, per-wave fixed region,
//    NO atomics -> deterministic): mask==1 -> out=1.0 in loop; mask==2 ->
//    (idx,d) entry. Epi runs threefry densely on ~50% sites only.
// ---------------------------------------------------------------------------

#define BB 4
#define LLEN 512
#define DD 256
#define HH 128

#define TWO_LOG2E 2.8853900817779268f   // 2*log2(e)
#define LOG2E_100 144.26950408889634f   // 100*log2(e)

#define NWAVES 2048        // attn_loop total waves; one entry region each
#define REGION 512         // 8 slots x 64 lanes per wave

__device__ __forceinline__ uint32_t rotl32(uint32_t v, int r) {
  return __builtin_amdgcn_alignbit(v, v, 32 - r);   // rotl: {v,v} >> (32-r)
}

// Threefry-2x32, key = (0, 42)
__device__ __forceinline__ void tf2x32(uint32_t x0, uint32_t x1,
                                       uint32_t& o0, uint32_t& o1) {
  const uint32_t k0 = 0u;
  const uint32_t k1 = 42u;
  const uint32_t k2 = 0x1BD11BDAu ^ k0 ^ k1;

  x0 += k0; x1 += k1;
#define TFR(r) { x0 += x1; x1 = rotl32(x1, (r)); x1 ^= x0; }
  TFR(13) TFR(15) TFR(26) TFR(6)
  x0 += k1; x1 += k2 + 1u;
  TFR(17) TFR(29) TFR(16) TFR(24)
  x0 += k2; x1 += k0 + 2u;
  TFR(13) TFR(15) TFR(26) TFR(6)
  x0 += k0; x1 += k1 + 3u;
  TFR(17) TFR(29) TFR(16) TFR(24)
  x0 += k1; x1 += k2 + 4u;
  TFR(13) TFR(15) TFR(26) TFR(6)
  x0 += k2; x1 += k0 + 5u;
#undef TFR
  o0 = x0; o1 = x1;
}

// u in (0,1) from jax partitionable random_bits (counter (0,flat), o0^o1)
__device__ __forceinline__ float jax_u01(uint32_t flat) {
  uint32_t o0, o1;
  tf2x32(0u, flat, o0, o1);
  const uint32_t bits = o0 ^ o1;
  const float f = __uint_as_float((bits >> 9) | 0x3F800000u) - 1.0f;
  return fmaxf(f, 1.17549435e-38f);
}

// ---------------------------------------------------------------------------
// Kernel A: projections -> EQ = exp2(c * q.Wq^T), EK = exp2(c * k.Wk^T).
// (identical to R9-R11; ~5us, not dominant)
// ---------------------------------------------------------------------------
__global__ __launch_bounds__(128) void proj_kernel(
    const float* __restrict__ queries, const float* __restrict__ keys,
    const float* __restrict__ Wq, const float* __restrict__ Wk,
    float* __restrict__ EQ, float* __restrict__ EK) {
  const int blk = blockIdx.x;
  const bool isK = blk >= 512;
  const int rb = (isK ? blk - 512 : blk) * 4;
  const float* __restrict__ in = isK ? keys : queries;
  const float* __restrict__ W  = isK ? Wk : Wq;
  float* __restrict__ outp     = isK ? EK : EQ;

  __shared__ float rows[4][DD];
  const float4* in4 = reinterpret_cast<const float4*>(in + (size_t)rb * DD);
  float4* rows4 = reinterpret_cast<float4*>(&rows[0][0]);
  #pragma unroll
  for (int t = threadIdx.x; t < 4 * DD / 4; t += 128) rows4[t] = in4[t];
  __syncthreads();

  const int h = threadIdx.x;
  const float4* W4 = reinterpret_cast<const float4*>(W + (size_t)h * DD);
  float a0 = 0.f, a1 = 0.f, a2 = 0.f, a3 = 0.f;
  #pragma unroll 8
  for (int d4 = 0; d4 < DD / 4; ++d4) {
    const float4 w = W4[d4];
    const int d = d4 * 4;
    a0 = fmaf(w.x, rows[0][d], fmaf(w.y, rows[0][d+1], fmaf(w.z, rows[0][d+2], fmaf(w.w, rows[0][d+3], a0))));
    a1 = fmaf(w.x, rows[1][d], fmaf(w.y, rows[1][d+1], fmaf(w.z, rows[1][d+2], fmaf(w.w, rows[1][d+3], a1))));
    a2 = fmaf(w.x, rows[2][d], fmaf(w.y, rows[2][d+1], fmaf(w.z, rows[2][d+2], fmaf(w.w, rows[2][d+3], a2))));
    a3 = fmaf(w.x, rows[3][d], fmaf(w.y, rows[3][d+1], fmaf(w.z, rows[3][d+2], fmaf(w.w, rows[3][d+3], a3))));
  }
  float* orow = outp + (size_t)rb * HH + h;
  orow[0 * HH] = __builtin_amdgcn_exp2f(a0 * TWO_LOG2E);
  orow[1 * HH] = __builtin_amdgcn_exp2f(a1 * TWO_LOG2E);
  orow[2 * HH] = __builtin_amdgcn_exp2f(a2 * TWO_LOG2E);
  orow[3 * HH] = __builtin_amdgcn_exp2f(a3 * TWO_LOG2E);
}

// ---------------------------------------------------------------------------
// Shared-rcp 4-group site macro (identical to R9-R11, passing)
// ---------------------------------------------------------------------------
#define GRP(accv, qv, kv, wd) {                                       \
    float4 A_;                                                        \
    A_.x = fmaf((qv).x, (kv).x, 1.0f);                                \
    A_.y = fmaf((qv).y, (kv).y, 1.0f);                                \
    A_.z = fmaf((qv).z, (kv).z, 1.0f);                                \
    A_.w = fmaf((qv).w, (kv).w, 1.0f);                                \
    const float p01_ = A_.x * A_.y;                                   \
    const float p23_ = A_.z * A_.w;                                   \
    const float n01_ = fmaf((wd).x, A_.y, (wd).y * A_.x);             \
    const float n23_ = fmaf((wd).z, A_.w, (wd).w * A_.z);             \
    const float num_ = fmaf(n01_, p23_, n23_ * p01_);                 \
    const float rc_  = __builtin_amdgcn_rcpf(p01_ * p23_);            \
    (accv) = fmaf(num_, rc_, (accv)); }

// ---------------------------------------------------------------------------
// Kernel B1: 32i x 64j tile (grid 16x8x4 = 512 blocks), 256 thr,
// 8 outputs/thread (4i x 2j). Wave-local compaction of mask==2 sites.
// ---------------------------------------------------------------------------
__global__ __launch_bounds__(256) void attn_loop(
    const float* __restrict__ EQ, const float* __restrict__ EK,
    const int* __restrict__ mask, const float* __restrict__ Wv,
    float* __restrict__ out, uint32_t* __restrict__ counts,
    uint2* __restrict__ entbuf) {
  __shared__ float4 QL[32][33];
  __shared__ float4 KL[64][33];
  __shared__ float4 wdL[32];

  const int bi = blockIdx.x, bj = blockIdx.y, b = blockIdx.z;
  const int i0 = bi * 32, j0 = bj * 64;

  const float4* Q4 = reinterpret_cast<const float4*>(EQ) + ((size_t)b * LLEN + i0) * (HH / 4);
  const float4* K4 = reinterpret_cast<const float4*>(EK) + ((size_t)b * LLEN + j0) * (HH / 4);
  for (int t = threadIdx.x; t < 1024 + 2048; t += 256) {
    if (t < 1024) {
      QL[t >> 5][t & 31] = Q4[t];
    } else {
      const int u = t - 1024;
      KL[u >> 5][u & 31] = K4[u];
    }
  }
  if (threadIdx.x < 32) {
    const float4 w0 = reinterpret_cast<const float4*>(Wv)[threadIdx.x];
    const float4 w1 = reinterpret_cast<const float4*>(Wv)[32 + threadIdx.x];
    float4 wd; wd.x = w0.x - w1.x; wd.y = w0.y - w1.y;
    wd.z = w0.z - w1.z; wd.w = w0.w - w1.w;
    wdL[threadIdx.x] = wd;
  }
  __syncthreads();

  const int jj = threadIdx.x & 31;   // cols j0+jj, j0+jj+32
  const int ib = threadIdx.x >> 5;   // rows ib, ib+8, ib+16, ib+24 (0..7 base)

  // mask prefetch (8 loads, hidden under loop)
  const uint32_t row0 = (uint32_t)b * LLEN + i0 + ib;
  const uint32_t col0 = j0 + jj;
  int mreg[4][2];
  #pragma unroll
  for (int r = 0; r < 4; ++r)
    #pragma unroll
    for (int c = 0; c < 2; ++c)
      mreg[r][c] = mask[(row0 + 8u * r) * LLEN + col0 + 32u * c];

  float Swd = 0.f;
  #pragma unroll
  for (int t = 0; t < 32; ++t) {
    const float4 wd = wdL[t];
    Swd += (wd.x + wd.y) + (wd.z + wd.w);
  }

  float acc[4][2] = {{0.f,0.f},{0.f,0.f},{0.f,0.f},{0.f,0.f}};

  #pragma unroll 4
  for (int h4 = 0; h4 < HH / 4; ++h4) {
    const float4 kv0 = KL[jj][h4];
    const float4 kv1 = KL[jj + 32][h4];
    const float4 wd  = wdL[h4];
    const float4 qv0 = QL[ib][h4];
    const float4 qv1 = QL[ib + 8][h4];
    const float4 qv2 = QL[ib + 16][h4];
    const float4 qv3 = QL[ib + 24][h4];
    GRP(acc[0][0], qv0, kv0, wd) GRP(acc[0][1], qv0, kv1, wd)
    GRP(acc[1][0], qv1, kv0, wd) GRP(acc[1][1], qv1, kv1, wd)
    GRP(acc[2][0], qv2, kv0, wd) GRP(acc[2][1], qv2, kv1, wd)
    GRP(acc[3][0], qv3, kv0, wd) GRP(acc[3][1], qv3, kv1, wd)
  }

  // wave-local compaction: mask==1 -> out=1.0 now; mask==2 -> (idx, d) entry
  const int lane = threadIdx.x & 63;
  const unsigned long long lanemask_lt = (1ull << lane) - 1ull;
  const uint32_t wave_id =
      (((uint32_t)blockIdx.z * gridDim.y + blockIdx.y) * gridDim.x + blockIdx.x) * 4u
      + (threadIdx.x >> 6);
  uint2* __restrict__ reg = entbuf + (size_t)wave_id * REGION;

  uint32_t off = 0;
  #pragma unroll
  for (int r = 0; r < 4; ++r) {
    #pragma unroll
    for (int c = 0; c < 2; ++c) {
      const uint32_t idx = (row0 + 8u * r) * LLEN + col0 + 32u * c;
      const bool need = (mreg[r][c] >= 2);
      const unsigned long long bal = __ballot(need);
      if (need) {
        const uint32_t rank = (uint32_t)__popcll(bal & lanemask_lt);
        uint2 ent;
        ent.x = idx;
        ent.y = __float_as_uint(fmaf(-2.0f, acc[r][c], Swd));  // d value
        reg[off + rank] = ent;
      } else {
        out[idx] = 1.0f;
      }
      off += (uint32_t)__popcll(bal);
    }
  }
  if (lane == 0) counts[wave_id] = off;
}

// ---------------------------------------------------------------------------
// Kernel B2: dense epilogue over compacted entries. One wave per region.
// grid 512 x 256thr = 2048 waves = NWAVES regions.
// ---------------------------------------------------------------------------
__global__ __launch_bounds__(256) void attn_epi(
    const uint32_t* __restrict__ counts, const uint2* __restrict__ entbuf,
    float* __restrict__ out) {
  const int lane = threadIdx.x & 63;
  const uint32_t g = (uint32_t)blockIdx.x * 4u + (threadIdx.x >> 6);
  const uint32_t cnt = counts[g];
  if (cnt == 0) return;
  const uint2* __restrict__ reg = entbuf + (size_t)g * REGION;

  const int iters = (int)((cnt + 63u) >> 6);
  #pragma unroll 2
  for (int k = 0; k < iters; ++k) {
    const uint32_t e = (uint32_t)k * 64u + (uint32_t)lane;
    const bool valid = e < cnt;
    const uint32_t eL = valid ? e : (cnt - 1u);
    const uint2 ent = reg[eL];

    const float dv = __uint_as_float(ent.y);
    const float l0 = __log2f(jax_u01(ent.x * 2u));
    const float l1 = __log2f(jax_u01(ent.x * 2u + 1u));
    const float rl = l1 * __builtin_amdgcn_rcpf(l0);
    const float dl = __log2f(rl);
    const float t  = fmaf(dv, LOG2E_100, 100.0f * dl);
    const float o  = __builtin_amdgcn_rcpf(1.0f + __builtin_amdgcn_exp2f(-t));
    if (valid) out[ent.x] = o;
  }
}

extern "C" void kernel_launch(void* const* d_in, const int* in_sizes, int n_in,
                              void* d_out, int out_size, void* d_ws, size_t ws_size,
                              hipStream_t stream) {
  const float* queries = (const float*)d_in[0];
  const float* keys    = (const float*)d_in[1];
  const int*   mask    = (const int*)d_in[2];
  const float* Wq      = (const float*)d_in[3];
  const float* Wk      = (const float*)d_in[4];
  const float* Wv      = (const float*)d_in[5];
  float* out = (float*)d_out;

  float* EQ = (float*)d_ws;                         // 1 MB
  float* EK = EQ + (size_t)BB * LLEN * HH;          // 1 MB
  uint32_t* counts = (uint32_t*)(EK + (size_t)BB * LLEN * HH);  // 8 KB (pad 16KB)
  uint2* entbuf = (uint2*)((char*)counts + 16384);  // 2048*512*8B = 8.4 MB

  proj_kernel<<<dim3(1024), dim3(128), 0, stream>>>(
      queries, keys, Wq, Wk, EQ, EK);
  attn_loop<<<dim3(LLEN / 32, LLEN / 64, BB), dim3(256), 0, stream>>>(
      EQ, EK, mask, Wv, out, counts, entbuf);
  attn_epi<<<dim3(NWAVES / 4), dim3(256), 0, stream>>>(
      counts, entbuf, out);
}

// Round 13
// 42.129 us; speedup vs baseline: 1.4595x; 1.1208x over previous
//
#include <hip/hip_runtime.h>
#include <stdint.h>

// ---------------------------------------------------------------------------
// AdditiveAttention (Bahdanau) + gumbel-softmax(tau=0.01), channel 0.
//
// out[b,i,j] = (mask==1) ? 1.0 : sigmoid((d + g0 - g1)*100),
//   d = sum_h tanh(q+k)*(w0-w1);  g bit-exact jax threefry (verified R3-R12).
//
// R13: dense gumbel pre-pass + fully-coalesced fused epilogue.
// R12 lesson: compacted epilogue writes were scattered 4B stores (~64B line
// each -> ~10us hidden write traffic). Now:
//   prep_kernel (ONE dispatch, heterogeneous grid):
//     blocks <1024: proj -> EQ=exp2(c q.Wq^T), EK=exp2(c k.Wk^T)  (R8 code)
//     blocks >=1024: dense G[s] = 100*(log2 l1 - log2 l0) for ALL sites,
//       threefry dense, coalesced writes, no mask.
//   attn_kernel: R12 32ix64j loop + light epilogue: read G (coalesced),
//     one fmaf+exp2+rcp, branchless select, coalesced out writes (R9 prop).
// 2 dispatches total (was 4). Site arithmetic bit-identical to R9-R12.
// ---------------------------------------------------------------------------

#define BB 4
#define LLEN 512
#define DD 256
#define HH 128

#define TWO_LOG2E 2.8853900817779268f   // 2*log2(e)
#define LOG2E_100 144.26950408889634f   // 100*log2(e)

#define NSITES (BB * LLEN * LLEN)       // 1048576
#define GUMBEL_THREADS (NSITES / 2)     // 524288 threads, 2 sites each

__device__ __forceinline__ uint32_t rotl32(uint32_t v, int r) {
  return __builtin_amdgcn_alignbit(v, v, 32 - r);
}

// Threefry-2x32, key = (0, 42)
__device__ __forceinline__ void tf2x32(uint32_t x0, uint32_t x1,
                                       uint32_t& o0, uint32_t& o1) {
  const uint32_t k0 = 0u;
  const uint32_t k1 = 42u;
  const uint32_t k2 = 0x1BD11BDAu ^ k0 ^ k1;

  x0 += k0; x1 += k1;
#define TFR(r) { x0 += x1; x1 = rotl32(x1, (r)); x1 ^= x0; }
  TFR(13) TFR(15) TFR(26) TFR(6)
  x0 += k1; x1 += k2 + 1u;
  TFR(17) TFR(29) TFR(16) TFR(24)
  x0 += k2; x1 += k0 + 2u;
  TFR(13) TFR(15) TFR(26) TFR(6)
  x0 += k0; x1 += k1 + 3u;
  TFR(17) TFR(29) TFR(16) TFR(24)
  x0 += k1; x1 += k2 + 4u;
  TFR(13) TFR(15) TFR(26) TFR(6)
  x0 += k2; x1 += k0 + 5u;
#undef TFR
  o0 = x0; o1 = x1;
}

// u in (0,1) from jax partitionable random_bits (counter (0,flat), o0^o1)
__device__ __forceinline__ float jax_u01(uint32_t flat) {
  uint32_t o0, o1;
  tf2x32(0u, flat, o0, o1);
  const uint32_t bits = o0 ^ o1;
  const float f = __uint_as_float((bits >> 9) | 0x3F800000u) - 1.0f;
  return fmaxf(f, 1.17549435e-38f);
}

// ---------------------------------------------------------------------------
// prep_kernel: heterogeneous grid.
//   blk < 512      : Q proj, rows 4*blk..4*blk+3
//   512 <= blk<1024: K proj
//   blk >= 1024    : gumbel pre-pass, 128 thr x 2 sites per block
// ---------------------------------------------------------------------------
__global__ __launch_bounds__(128) void prep_kernel(
    const float* __restrict__ queries, const float* __restrict__ keys,
    const float* __restrict__ Wq, const float* __restrict__ Wk,
    float* __restrict__ EQ, float* __restrict__ EK, float* __restrict__ G) {
  const int blk = blockIdx.x;

  if (blk >= 1024) {
    // ---- dense gumbel: G[s] = 100*(log2(l1) - log2(l0)), l_i = log2(u_i)
    const uint32_t base = (uint32_t)(blk - 1024) * 128u + threadIdx.x;
    #pragma unroll
    for (int rep = 0; rep < 2; ++rep) {
      const uint32_t s = base + (uint32_t)rep * GUMBEL_THREADS;
      const float l0 = __log2f(jax_u01(s * 2u));
      const float l1 = __log2f(jax_u01(s * 2u + 1u));
      const float rl = l1 * __builtin_amdgcn_rcpf(l0);
      G[s] = 100.0f * __log2f(rl);
    }
    return;
  }

  // ---- projection path (R8-R12 verbatim)
  const bool isK = blk >= 512;
  const int rb = (isK ? blk - 512 : blk) * 4;
  const float* __restrict__ in = isK ? keys : queries;
  const float* __restrict__ W  = isK ? Wk : Wq;
  float* __restrict__ outp     = isK ? EK : EQ;

  __shared__ float rows[4][DD];
  const float4* in4 = reinterpret_cast<const float4*>(in + (size_t)rb * DD);
  float4* rows4 = reinterpret_cast<float4*>(&rows[0][0]);
  #pragma unroll
  for (int t = threadIdx.x; t < 4 * DD / 4; t += 128) rows4[t] = in4[t];
  __syncthreads();

  const int h = threadIdx.x;
  const float4* W4 = reinterpret_cast<const float4*>(W + (size_t)h * DD);
  float a0 = 0.f, a1 = 0.f, a2 = 0.f, a3 = 0.f;
  #pragma unroll 8
  for (int d4 = 0; d4 < DD / 4; ++d4) {
    const float4 w = W4[d4];
    const int d = d4 * 4;
    a0 = fmaf(w.x, rows[0][d], fmaf(w.y, rows[0][d+1], fmaf(w.z, rows[0][d+2], fmaf(w.w, rows[0][d+3], a0))));
    a1 = fmaf(w.x, rows[1][d], fmaf(w.y, rows[1][d+1], fmaf(w.z, rows[1][d+2], fmaf(w.w, rows[1][d+3], a1))));
    a2 = fmaf(w.x, rows[2][d], fmaf(w.y, rows[2][d+1], fmaf(w.z, rows[2][d+2], fmaf(w.w, rows[2][d+3], a2))));
    a3 = fmaf(w.x, rows[3][d], fmaf(w.y, rows[3][d+1], fmaf(w.z, rows[3][d+2], fmaf(w.w, rows[3][d+3], a3))));
  }
  float* orow = outp + (size_t)rb * HH + h;
  orow[0 * HH] = __builtin_amdgcn_exp2f(a0 * TWO_LOG2E);
  orow[1 * HH] = __builtin_amdgcn_exp2f(a1 * TWO_LOG2E);
  orow[2 * HH] = __builtin_amdgcn_exp2f(a2 * TWO_LOG2E);
  orow[3 * HH] = __builtin_amdgcn_exp2f(a3 * TWO_LOG2E);
}

// ---------------------------------------------------------------------------
// Shared-rcp 4-group site macro (identical to R9-R12, passing)
// ---------------------------------------------------------------------------
#define GRP(accv, qv, kv, wd) {                                       \
    float4 A_;                                                        \
    A_.x = fmaf((qv).x, (kv).x, 1.0f);                                \
    A_.y = fmaf((qv).y, (kv).y, 1.0f);                                \
    A_.z = fmaf((qv).z, (kv).z, 1.0f);                                \
    A_.w = fmaf((qv).w, (kv).w, 1.0f);                                \
    const float p01_ = A_.x * A_.y;                                   \
    const float p23_ = A_.z * A_.w;                                   \
    const float n01_ = fmaf((wd).x, A_.y, (wd).y * A_.x);             \
    const float n23_ = fmaf((wd).z, A_.w, (wd).w * A_.z);             \
    const float num_ = fmaf(n01_, p23_, n23_ * p01_);                 \
    const float rc_  = __builtin_amdgcn_rcpf(p01_ * p23_);            \
    (accv) = fmaf(num_, rc_, (accv)); }

// ---------------------------------------------------------------------------
// attn_kernel: 32i x 64j tile (grid 16x8x4 = 512 blocks), 256 thr,
// 8 outputs/thread (4i x 2j). Light fused epilogue, fully coalesced.
// ---------------------------------------------------------------------------
__global__ __launch_bounds__(256) void attn_kernel(
    const float* __restrict__ EQ, const float* __restrict__ EK,
    const int* __restrict__ mask, const float* __restrict__ Wv,
    const float* __restrict__ G, float* __restrict__ out) {
  __shared__ float4 QL[32][33];
  __shared__ float4 KL[64][33];
  __shared__ float4 wdL[32];

  const int bi = blockIdx.x, bj = blockIdx.y, b = blockIdx.z;
  const int i0 = bi * 32, j0 = bj * 64;

  const float4* Q4 = reinterpret_cast<const float4*>(EQ) + ((size_t)b * LLEN + i0) * (HH / 4);
  const float4* K4 = reinterpret_cast<const float4*>(EK) + ((size_t)b * LLEN + j0) * (HH / 4);
  for (int t = threadIdx.x; t < 1024 + 2048; t += 256) {
    if (t < 1024) {
      QL[t >> 5][t & 31] = Q4[t];
    } else {
      const int u = t - 1024;
      KL[u >> 5][u & 31] = K4[u];
    }
  }
  if (threadIdx.x < 32) {
    const float4 w0 = reinterpret_cast<const float4*>(Wv)[threadIdx.x];
    const float4 w1 = reinterpret_cast<const float4*>(Wv)[32 + threadIdx.x];
    float4 wd; wd.x = w0.x - w1.x; wd.y = w0.y - w1.y;
    wd.z = w0.z - w1.z; wd.w = w0.w - w1.w;
    wdL[threadIdx.x] = wd;
  }
  __syncthreads();

  const int jj = threadIdx.x & 31;   // cols j0+jj, j0+jj+32
  const int ib = threadIdx.x >> 5;   // rows ib, ib+8, ib+16, ib+24

  // prefetch mask + G (16 coalesced loads, hidden under the h4 loop)
  const uint32_t row0 = (uint32_t)b * LLEN + i0 + ib;
  const uint32_t col0 = j0 + jj;
  int   mreg[4][2];
  float greg[4][2];
  #pragma unroll
  for (int r = 0; r < 4; ++r)
    #pragma unroll
    for (int c = 0; c < 2; ++c) {
      const uint32_t idx = (row0 + 8u * r) * LLEN + col0 + 32u * c;
      mreg[r][c] = mask[idx];
      greg[r][c] = G[idx];
    }

  float Swd = 0.f;
  #pragma unroll
  for (int t = 0; t < 32; ++t) {
    const float4 wd = wdL[t];
    Swd += (wd.x + wd.y) + (wd.z + wd.w);
  }

  float acc[4][2] = {{0.f,0.f},{0.f,0.f},{0.f,0.f},{0.f,0.f}};

  #pragma unroll 4
  for (int h4 = 0; h4 < HH / 4; ++h4) {
    const float4 kv0 = KL[jj][h4];
    const float4 kv1 = KL[jj + 32][h4];
    const float4 wd  = wdL[h4];
    const float4 qv0 = QL[ib][h4];
    const float4 qv1 = QL[ib + 8][h4];
    const float4 qv2 = QL[ib + 16][h4];
    const float4 qv3 = QL[ib + 24][h4];
    GRP(acc[0][0], qv0, kv0, wd) GRP(acc[0][1], qv0, kv1, wd)
    GRP(acc[1][0], qv1, kv0, wd) GRP(acc[1][1], qv1, kv1, wd)
    GRP(acc[2][0], qv2, kv0, wd) GRP(acc[2][1], qv2, kv1, wd)
    GRP(acc[3][0], qv3, kv0, wd) GRP(acc[3][1], qv3, kv1, wd)
  }

  // light epilogue: coalesced writes, branchless select
  #pragma unroll
  for (int r = 0; r < 4; ++r) {
    #pragma unroll
    for (int c = 0; c < 2; ++c) {
      const uint32_t idx = (row0 + 8u * r) * LLEN + col0 + 32u * c;
      const float d_ = fmaf(-2.0f, acc[r][c], Swd);
      const float t_ = fmaf(d_, LOG2E_100, greg[r][c]);
      const float o_ = __builtin_amdgcn_rcpf(1.0f + __builtin_amdgcn_exp2f(-t_));
      out[idx] = (mreg[r][c] >= 2) ? o_ : 1.0f;
    }
  }
}

extern "C" void kernel_launch(void* const* d_in, const int* in_sizes, int n_in,
                              void* d_out, int out_size, void* d_ws, size_t ws_size,
                              hipStream_t stream) {
  const float* queries = (const float*)d_in[0];
  const float* keys    = (const float*)d_in[1];
  const int*   mask    = (const int*)d_in[2];
  const float* Wq      = (const float*)d_in[3];
  const float* Wk      = (const float*)d_in[4];
  const float* Wv      = (const float*)d_in[5];
  float* out = (float*)d_out;

  float* EQ = (float*)d_ws;                 // 1 MB
  float* EK = EQ + (size_t)BB * LLEN * HH;  // 1 MB
  float* G  = EK + (size_t)BB * LLEN * HH;  // 4.19 MB (per-site gumbel diff)

  // 1024 proj blocks + 4096 gumbel blocks, one dispatch
  prep_kernel<<<dim3(1024 + GUMBEL_THREADS / 128), dim3(128), 0, stream>>>(
      queries, keys, Wq, Wk, EQ, EK, G);
  attn_kernel<<<dim3(LLEN / 32, LLEN / 64, BB), dim3(256), 0, stream>>>(
      EQ, EK, mask, Wv, G, out);
}